// Round 15
// baseline (189.929 us; speedup 1.0000x reference)
//
#include <hip/hip_runtime.h>
#include <hip/hip_bf16.h>

// Masked SDPA, B=16, NQ=2048, NKV=2048, D=64, f32 in/out, bf16 MFMA compute.
// R15 = R13 body + oversubscribed split-KV schedule:
//  - grid 512 (2x CU count): block = (batch-rank, 128q-tile, kv-half).
//    Each wave handles kv tiles {4k + 2*half + hh} -> <=8 iters/block.
//    256 resident + 256 queued -> HW refills CUs as blocks retire.
//  - inline wave-parallel batch ranking (16 shuffles + ballot, NO sched
//    kernel -- R14's 1-thread sched kernel cost ~6us serial).
//  - mapping g: x=g&7 (XCD %8 heuristic), alternating heavy(rank x) /
//    light(rank 15-x) -> per-XCD only 2 batches (1MB L2, R13's affinity)
//    AND pair-balanced per-XCD work, heavies dispatched first (LPT).
//  - (b,qt) halves merge via ws partials + device-scope flag: second
//    finisher merges (order-fixed formula -> deterministic) and writes O.
// R13 body verbatim: chain-split A/B accumulators, reg-direct fragment
// loads, swapped 32x32 QK^T, in-reg P (cvt_pk+permlane32_swap), T13
// defer-max, raw v_exp_f32, K-prefetch reg double-buffer, mask fast-path.

typedef __attribute__((ext_vector_type(8))) short short8;
typedef __attribute__((ext_vector_type(4))) short short4v;
typedef __attribute__((ext_vector_type(4))) float float4v;
typedef __attribute__((ext_vector_type(16))) float f32x16;

#define BATCH 16
#define NQ 2048
#define NKV 2048
#define DH 64
#define KVB 64
#define NTILES (NKV / KVB)          // 32
#define TILE_ELEMS (KVB * DH)       // 4096 bf16 = 8 KB per tile per array
#define NEG_INF -1e20f
// (1/sqrt(64)) * log2(e)
#define SCALE_LOG2 0.180336880111120f

__device__ __forceinline__ short f2bf(float x) {
    union { float f; unsigned u; } v; v.f = x;
    unsigned r = (v.u + 0x7fffu + ((v.u >> 16) & 1u)) >> 16;
    return (short)r;
}

__device__ __forceinline__ short8 cvt8(float4v a, float4v b) {
    short8 r;
    r[0] = f2bf(a[0]); r[1] = f2bf(a[1]); r[2] = f2bf(a[2]); r[3] = f2bf(a[3]);
    r[4] = f2bf(b[0]); r[5] = f2bf(b[1]); r[6] = f2bf(b[2]); r[7] = f2bf(b[3]);
    return r;
}

__device__ __forceinline__ float fexp2(float x) {
    float r; asm("v_exp_f32 %0, %1" : "=v"(r) : "v"(x)); return r;
}

// ---- prep: f32 -> bf16 fragment-sequential layouts (unchanged) -------------
__global__ __launch_bounds__(256) void prep_kernel(
    const float* __restrict__ K, const float* __restrict__ V,
    const int* __restrict__ valid_lens,
    short* __restrict__ Kf, short* __restrict__ Vf)
{
    const int b    = blockIdx.x >> 5;
    const int tile = blockIdx.x & 31;
    const int vlen = valid_lens[b];
    const int nkv  = (vlen == 0) ? NKV : vlen;
    if (tile * KVB >= nkv) return;          // never read by attn

    const int tid = threadIdx.x;
    const int ln  = tid & 63;
    const int l31 = ln & 31;
    const int hi8 = (ln >> 5) * 8;
    const size_t gbase = ((size_t)b * NKV + (size_t)tile * KVB) * DH;
    short* kt = Kf + (((size_t)b * NTILES + tile) * TILE_ELEMS);
    short* vt = Vf + (((size_t)b * NTILES + tile) * TILE_ELEMS);

#pragma unroll
    for (int s = 0; s < 2; ++s) {           // K frags: slots s*256+tid
        const int kk = tid >> 6;            // 0..3
        const int kv = s * 32 + l31;
        const int d  = kk * 16 + hi8;
        const float* p = K + gbase + (size_t)kv * DH + d;
        *reinterpret_cast<short8*>(kt + (s * 256 + tid) * 8) =
            cvt8(*reinterpret_cast<const float4v*>(p),
                 *reinterpret_cast<const float4v*>(p + 4));
    }
    {   // V: 4x4 float4 transpose -> short4 writes into frag-sequential layout
        const int kv0 = (tid >> 4) << 2;    // 0..60 step 4
        const int d0  = (tid & 15) << 2;    // 0..60 step 4
        const float* p = V + gbase + (size_t)kv0 * DH + d0;
        float4v r0 = *reinterpret_cast<const float4v*>(p);
        float4v r1 = *reinterpret_cast<const float4v*>(p + DH);
        float4v r2 = *reinterpret_cast<const float4v*>(p + 2 * DH);
        float4v r3 = *reinterpret_cast<const float4v*>(p + 3 * DH);
        const int ks  = kv0 >> 4;
        const int hiv = (kv0 >> 3) & 1;
        const int j0  = kv0 & 7;            // 0 or 4
#pragma unroll
        for (int k = 0; k < 4; ++k) {
            const int d    = d0 + k;
            const int lanev = (d & 31) + 32 * hiv;
            short4v w;
            w[0] = f2bf(r0[k]); w[1] = f2bf(r1[k]);
            w[2] = f2bf(r2[k]); w[3] = f2bf(r3[k]);
            *reinterpret_cast<short4v*>(
                vt + (((d >> 5) * 4 + ks) * 64 + lanev) * 8 + j0) = w;
        }
    }
}

// ------------- attn: 8 waves = 4 qsub(32 q-rows) x 2 kv-streams -------------
__global__ __launch_bounds__(512) void attn_fwd_kernel(
    const float* __restrict__ Q,
    const short* __restrict__ Kf,
    const short* __restrict__ Vf,
    const int* __restrict__ vl,
    float* __restrict__ O,
    float* __restrict__ Po,       // partials [b][qt][half][128][64]
    float2* __restrict__ Pm,      // [b][qt][half][128] = (m, l)
    int* __restrict__ flags)      // [b*16+qt]
{
    __shared__ float  mrg[4][2048];        // in-block stream merge (32 KB)
    __shared__ float2 mlb[4][32];
    __shared__ int s_second;

    const int tid  = threadIdx.x;
    const int wave = tid >> 6;
    const int lane = tid & 63;
    const int l31  = lane & 31;
    const int hi   = lane >> 5;
    const int hh   = wave >> 2;            // kv-stream within block
    const int qsub = wave & 3;             // q sub-tile (32 rows)

    // ---- block decode: x = XCD (%8 heuristic), alternate heavy/light ----
    const int x    = blockIdx.x & 7;
    const int pos  = blockIdx.x >> 3;      // 0..63
    const int sub  = pos >> 1;             // 0..31
    const int qt   = sub & 15;
    const int half = sub >> 4;             // kv half (tiles mod 4: 2h,2h+1)
    const int wrank = (pos & 1) ? (15 - x) : x;

    // ---- inline rank -> batch (wave-parallel, ~30 instrs) ----
    int tv;
    {
        const int v  = vl[lane & 15];
        const int nk = (v == 0) ? NKV : v;
        tv = (nk + KVB - 1) >> 6;
    }
    int rank = 0;
#pragma unroll
    for (int j = 0; j < 16; ++j) {
        const int tj = __shfl(tv, j, 64);
        rank += (tj > tv) || (tj == tv && j < (lane & 15));
    }
    const unsigned long long mk = __ballot((lane < 16) && (rank == wrank));
    const int b = __ffsll(mk) - 1;

    const int vlen  = vl[b];
    const int nkv   = (vlen == 0) ? NKV : vlen;
    const int tiles = (nkv + KVB - 1) >> 6;
    const int tbase = 2 * half + hh;       // my tile stream: tbase + 4k
    const int nh    = (tiles > tbase) ? ((tiles - tbase + 3) >> 2) : 0;
    const int qbase = qt * 128 + qsub * 32;

    // Q B-fragments (scale folded): lane col q=l31, k-elems d = kk*16+hi*8+j
    const float* Qb = Q + ((size_t)b * NQ + qbase + l31) * DH;
    short8 qfrag[4];
#pragma unroll
    for (int kk = 0; kk < 4; ++kk) {
        const float* p = Qb + kk * 16 + hi * 8;
        float4v a = *reinterpret_cast<const float4v*>(p);
        float4v c = *reinterpret_cast<const float4v*>(p + 4);
#pragma unroll
        for (int j = 0; j < 4; ++j) { a[j] *= SCALE_LOG2; c[j] *= SCALE_LOG2; }
        qfrag[kk] = cvt8(a, c);
    }

    const short* Kfb = Kf + (size_t)b * NTILES * TILE_ELEMS + lane * 8;
    const short* Vfb = Vf + (size_t)b * NTILES * TILE_ELEMS + lane * 8;

    auto load_k = [&](short8 (&kf)[8], int tile) {
        const short* p = Kfb + (size_t)tile * TILE_ELEMS;
#pragma unroll
        for (int i = 0; i < 8; ++i)
            kf[i] = *reinterpret_cast<const short8*>(p + i * 512);
    };

    f32x16 acc_oA[2], acc_oB[2];
#pragma unroll
    for (int t = 0; t < 2; ++t)
#pragma unroll
        for (int r = 0; r < 16; ++r) { acc_oA[t][r] = 0.f; acc_oB[t][r] = 0.f; }
    float m = -INFINITY, lsum = 0.f;

    short8 kf0[8], kf1[8];

    auto body = [&](short8 (&kc)[8], short8 (&kn)[8], f32x16 (&am)[2], int it) {
        const int tile = 4 * it + tbase;

        short8 vfr[8];                     // body-local V fragments
        {
            const short* p = Vfb + (size_t)tile * TILE_ELEMS;
#pragma unroll
            for (int i = 0; i < 8; ++i)
                vfr[i] = *reinterpret_cast<const short8*>(p + i * 512);
        }

        // ---- S^T = K Q^T: lane owns q=l31, kv = 32s + (r&3)+8(r>>2)+4hi ----
        f32x16 acs[2];
#pragma unroll
        for (int s = 0; s < 2; ++s)
#pragma unroll
            for (int r = 0; r < 16; ++r) acs[s][r] = 0.f;
        __builtin_amdgcn_s_setprio(1);
#pragma unroll
        for (int s = 0; s < 2; ++s)
#pragma unroll
            for (int kk = 0; kk < 4; ++kk)
                acs[s] = __builtin_amdgcn_mfma_f32_32x32x16_bf16(
                    kc[s * 4 + kk], qfrag[kk], acs[s], 0, 0, 0);
        __builtin_amdgcn_s_setprio(0);

        if (it + 1 < nh) load_k(kn, 4 * (it + 1) + tbase);  // prefetch next K

        // ---- mask, skipped for fully-valid tiles (wave-uniform) ----
        if (vlen < (tile + 1) * KVB) {
            const int kvb0 = tile * KVB + 4 * hi;
#pragma unroll
            for (int s = 0; s < 2; ++s) {
                const int vlim = vlen - (kvb0 + s * 32);
#pragma unroll
                for (int r = 0; r < 16; ++r) {
                    const int rc = (r & 3) + 8 * (r >> 2);
                    acs[s][r] = (rc < vlim) ? acs[s][r] : NEG_INF;
                }
            }
        }

        // ---- row max: depth-5 tree + 1 shuffle ----
        float mx[8];
#pragma unroll
        for (int r = 0; r < 8; ++r)
            mx[r] = fmaxf(fmaxf(acs[0][r], acs[0][r + 8]),
                          fmaxf(acs[1][r], acs[1][r + 8]));
#pragma unroll
        for (int d = 4; d; d >>= 1)
#pragma unroll
            for (int r = 0; r < d; ++r) mx[r] = fmaxf(mx[r], mx[r + d]);
        float xv = mx[0];
        xv = fmaxf(xv, __shfl_xor(xv, 32, 64));

        // ---- T13 defer-max (rescale BOTH accumulator sets; rare) ----
        float mn = m;
        if (!__all(xv <= m + 8.f)) {
            mn = fmaxf(m, xv);
            const float alpha = fexp2(m - mn);   // m=-inf first -> 0
            m = mn;
            lsum *= alpha;
#pragma unroll
            for (int r = 0; r < 16; ++r) {
                const int rc = (r & 3) + 8 * (r >> 2);
                const float ar = __shfl(alpha, rc + 4 * hi, 64);
                acc_oA[0][r] *= ar; acc_oA[1][r] *= ar;
                acc_oB[0][r] *= ar; acc_oB[1][r] *= ar;
            }
        }

        // ---- P = 2^(s - mn); sum as tree + 1 shuffle ----
#pragma unroll
        for (int s = 0; s < 2; ++s)
#pragma unroll
            for (int r = 0; r < 16; ++r) acs[s][r] = fexp2(acs[s][r] - mn);
        float sm[8];
#pragma unroll
        for (int r = 0; r < 8; ++r)
            sm[r] = (acs[0][r] + acs[0][r + 8]) + (acs[1][r] + acs[1][r + 8]);
#pragma unroll
        for (int d = 4; d; d >>= 1)
#pragma unroll
            for (int r = 0; r < d; ++r) sm[r] += sm[r + d];
        float rs = sm[0];
        rs += __shfl_xor(rs, 32, 64);
        lsum += rs;

        // ---- P -> bf16 packs (16 cvt_pk) ----
        unsigned pk[2][4][2];
#pragma unroll
        for (int s = 0; s < 2; ++s)
#pragma unroll
            for (int be = 0; be < 4; ++be)
#pragma unroll
                for (int c = 0; c < 2; ++c)
                    asm("v_cvt_pk_bf16_f32 %0, %1, %2"
                        : "=v"(pk[s][be][c])
                        : "v"(acs[s][4 * be + 2 * c]),
                          "v"(acs[s][4 * be + 2 * c + 1]));

        // ---- O(me) += P V: 8 permlane32_swap build A-frags in-register ----
        __builtin_amdgcn_s_setprio(1);
#pragma unroll
        for (int ks = 0; ks < 4; ++ks) {
            const int s = ks >> 1, g = ks & 1;
            unsigned w0 = pk[s][2 * g][0], w2 = pk[s][2 * g + 1][0];
            unsigned w1 = pk[s][2 * g][1], w3 = pk[s][2 * g + 1][1];
            asm("v_permlane32_swap_b32 %0, %1" : "+v"(w0), "+v"(w2));
            asm("v_permlane32_swap_b32 %0, %1" : "+v"(w1), "+v"(w3));
            union { unsigned u[4]; short8 s8; } pf;
            pf.u[0] = w0; pf.u[1] = w1; pf.u[2] = w2; pf.u[3] = w3;
#pragma unroll
            for (int t = 0; t < 2; ++t)
                am[t] = __builtin_amdgcn_mfma_f32_32x32x16_bf16(
                    pf.s8, vfr[t * 4 + ks], am[t], 0, 0, 0);
        }
        __builtin_amdgcn_s_setprio(0);
    };

    if (nh > 0) load_k(kf0, tbase);
    int it = 0;
    for (; it + 1 < nh; it += 2) {         // A/B alternate: independent chains
        body(kf0, kf1, acc_oA, it);
        body(kf1, kf0, acc_oB, it + 1);
    }
    if (it < nh) body(kf0, kf1, acc_oA, it);

#pragma unroll
    for (int t = 0; t < 2; ++t)
#pragma unroll
        for (int r = 0; r < 16; ++r) acc_oA[t][r] += acc_oB[t][r];

    // ---- in-block merge of the two kv-streams; hh==0 writes partial ----
    float* Pob  = Po + (((size_t)b * 16 + qt) * 2 + half) * (128 * 64);
    float2* Pmb = Pm + (((size_t)b * 16 + qt) * 2 + half) * 128;
    if (hh == 1) {
#pragma unroll
        for (int t = 0; t < 2; ++t)
#pragma unroll
            for (int r = 0; r < 16; ++r)
                mrg[qsub][(t * 16 + r) * 64 + lane] = acc_oA[t][r];
        if (lane < 32) mlb[qsub][lane] = float2{m, lsum};
    }
    __syncthreads();
    if (hh == 0) {
        const float2 o1 = mlb[qsub][l31];
        const float m1 = o1.x, l1 = o1.y;
        const float M  = fmaxf(m, m1);
        const float w0 = (lsum > 0.f) ? fexp2(m - M) : 0.f;
        const float w1 = (l1   > 0.f) ? fexp2(m1 - M) : 0.f;
        const float lp = lsum * w0 + l1 * w1;
#pragma unroll
        for (int r = 0; r < 16; ++r) {
            const int rc = (r & 3) + 8 * (r >> 2);
            const float a0r = __shfl(w0, rc + 4 * hi, 64);
            const float a1r = __shfl(w1, rc + 4 * hi, 64);
#pragma unroll
            for (int t = 0; t < 2; ++t) {
                const float oh = mrg[qsub][(t * 16 + r) * 64 + lane];
                Pob[(size_t)(qsub * 32 + rc + 4 * hi) * 64 + t * 32 + l31] =
                    acc_oA[t][r] * a0r + oh * a1r;
            }
        }
        if (lane < 32) Pmb[qsub * 32 + l31] = float2{M, lp};
    }

    // ---- cross-block flag protocol; second finisher merges + writes O ----
    __threadfence();                       // make my partial stores visible
    __syncthreads();
    if (tid == 0) {
        const int old = atomicAdd(&flags[b * 16 + qt], 1);
        s_second = (old == 1);
    }
    __syncthreads();
    if (s_second) {
        __threadfence();                   // acquire other block's partial
        const float*  P0 = Po + (((size_t)b * 16 + qt) * 2 + 0) * (128 * 64);
        const float*  P1 = Po + (((size_t)b * 16 + qt) * 2 + 1) * (128 * 64);
        const float2* M0 = Pm + (((size_t)b * 16 + qt) * 2 + 0) * 128;
        const float2* M1 = Pm + (((size_t)b * 16 + qt) * 2 + 1) * 128;
        const int q  = tid >> 2;           // 0..127
        const int dg = (tid & 3) << 4;     // 0,16,32,48
        const float2 c0 = M0[q], c1 = M1[q];
        const float Mf = fmaxf(c0.x, c1.x);
        const float w0 = (c0.y > 0.f) ? fexp2(c0.x - Mf) : 0.f;
        const float w1 = (c1.y > 0.f) ? fexp2(c1.x - Mf) : 0.f;
        const float Li = 1.f / (c0.y * w0 + c1.y * w1);
        float* Ob = O + ((size_t)b * NQ + qt * 128 + q) * DH + dg;
#pragma unroll
        for (int j = 0; j < 4; ++j) {
            float4v a = *reinterpret_cast<const float4v*>(P0 + (size_t)q * 64 + dg + 4 * j);
            float4v c = *reinterpret_cast<const float4v*>(P1 + (size_t)q * 64 + dg + 4 * j);
            float4v o;
#pragma unroll
            for (int k = 0; k < 4; ++k) o[k] = (a[k] * w0 + c[k] * w1) * Li;
            *reinterpret_cast<float4v*>(Ob + 4 * j) = o;
        }
    }
}

extern "C" void kernel_launch(void* const* d_in, const int* in_sizes, int n_in,
                              void* d_out, int out_size, void* d_ws, size_t ws_size,
                              hipStream_t stream) {
    const float* Q = (const float*)d_in[0];
    const float* K = (const float*)d_in[1];
    const float* V = (const float*)d_in[2];
    const int* vl  = (const int*)d_in[3];
    float* Out     = (float*)d_out;

    short*  Kws   = (short*)d_ws;                            // 4 MB
    short*  Vws   = Kws + (size_t)BATCH * NTILES * TILE_ELEMS; // 4 MB
    float*  Po    = (float*)((char*)d_ws + (8u << 20));      // 16 MB partials
    float2* Pm    = (float2*)((char*)d_ws + (24u << 20));    // 512 KB
    int*    flags = (int*)((char*)d_ws + (25u << 20));       // 1 KB

    hipMemsetAsync(flags, 0, 256 * sizeof(int), stream);
    prep_kernel<<<dim3(BATCH * NTILES), dim3(256), 0, stream>>>(K, V, vl, Kws, Vws);
    attn_fwd_kernel<<<dim3(512), dim3(512), 0, stream>>>(
        Q, Kws, Vws, vl, Out, Po, Pm, flags);
}

// Round 16
// 48.485 us; speedup vs baseline: 3.9173x; 3.9173x over previous
//
#include <hip/hip_runtime.h>
#include <hip/hip_bf16.h>

// Masked SDPA, B=16, NQ=2048, NKV=2048, D=64, f32 in/out, bf16 MFMA compute.
// R16 = R13 (best, 35.1us) + ONE change: explicit 1-tile-ahead QK^T pipeline.
// R13 was critical-path-limited (~4500cy/iter vs ~1060cy issue): QK^T chain ->
// softmax chain -> PV chain serial per body at 2 waves/SIMD. Now QK^T(t+1)
// (MFMA, independent: prefetched K + Q) issues between softmax(t) (VALU) and
// PV(t) -> MFMA pipe and VALU overlap across tiles. Two score register sets
// sA/sB; everything else byte-identical to R13 (chain-split A/B accumulators,
// reg-direct fragment loads from ws, swapped 32x32 QK^T, in-reg P via
// cvt_pk+permlane32_swap, T13 defer-max, raw v_exp_f32, LDS merge epilogue).
// R15 lesson encoded: NO cross-block fences/atomics (device-scope fence =
// L2 invalidate on gfx950 -> destroyed co-resident blocks' locality).

typedef __attribute__((ext_vector_type(8))) short short8;
typedef __attribute__((ext_vector_type(4))) short short4v;
typedef __attribute__((ext_vector_type(4))) float float4v;
typedef __attribute__((ext_vector_type(16))) float f32x16;

#define BATCH 16
#define NQ 2048
#define NKV 2048
#define DH 64
#define KVB 64
#define NTILES (NKV / KVB)          // 32
#define TILE_ELEMS (KVB * DH)       // 4096 bf16 = 8 KB per tile per array
#define NEG_INF -1e20f
// (1/sqrt(64)) * log2(e)
#define SCALE_LOG2 0.180336880111120f

__device__ __forceinline__ short f2bf(float x) {
    union { float f; unsigned u; } v; v.f = x;
    unsigned r = (v.u + 0x7fffu + ((v.u >> 16) & 1u)) >> 16;
    return (short)r;
}

__device__ __forceinline__ short8 cvt8(float4v a, float4v b) {
    short8 r;
    r[0] = f2bf(a[0]); r[1] = f2bf(a[1]); r[2] = f2bf(a[2]); r[3] = f2bf(a[3]);
    r[4] = f2bf(b[0]); r[5] = f2bf(b[1]); r[6] = f2bf(b[2]); r[7] = f2bf(b[3]);
    return r;
}

__device__ __forceinline__ float fexp2(float x) {
    float r; asm("v_exp_f32 %0, %1" : "=v"(r) : "v"(x)); return r;
}

// ---- prep: f32 -> bf16 fragment-sequential layouts (unchanged) -------------
__global__ __launch_bounds__(256) void prep_kernel(
    const float* __restrict__ K, const float* __restrict__ V,
    const int* __restrict__ valid_lens,
    short* __restrict__ Kf, short* __restrict__ Vf)
{
    const int b    = blockIdx.x >> 5;
    const int tile = blockIdx.x & 31;
    const int vlen = valid_lens[b];
    const int nkv  = (vlen == 0) ? NKV : vlen;
    if (tile * KVB >= nkv) return;          // never read by attn

    const int tid = threadIdx.x;
    const int ln  = tid & 63;
    const int l31 = ln & 31;
    const int hi8 = (ln >> 5) * 8;
    const size_t gbase = ((size_t)b * NKV + (size_t)tile * KVB) * DH;
    short* kt = Kf + (((size_t)b * NTILES + tile) * TILE_ELEMS);
    short* vt = Vf + (((size_t)b * NTILES + tile) * TILE_ELEMS);

#pragma unroll
    for (int s = 0; s < 2; ++s) {           // K frags: slots s*256+tid
        const int kk = tid >> 6;            // 0..3
        const int kv = s * 32 + l31;
        const int d  = kk * 16 + hi8;
        const float* p = K + gbase + (size_t)kv * DH + d;
        *reinterpret_cast<short8*>(kt + (s * 256 + tid) * 8) =
            cvt8(*reinterpret_cast<const float4v*>(p),
                 *reinterpret_cast<const float4v*>(p + 4));
    }
    {   // V: 4x4 float4 transpose -> short4 writes into frag-sequential layout
        const int kv0 = (tid >> 4) << 2;    // 0..60 step 4
        const int d0  = (tid & 15) << 2;    // 0..60 step 4
        const float* p = V + gbase + (size_t)kv0 * DH + d0;
        float4v r0 = *reinterpret_cast<const float4v*>(p);
        float4v r1 = *reinterpret_cast<const float4v*>(p + DH);
        float4v r2 = *reinterpret_cast<const float4v*>(p + 2 * DH);
        float4v r3 = *reinterpret_cast<const float4v*>(p + 3 * DH);
        const int ks  = kv0 >> 4;
        const int hiv = (kv0 >> 3) & 1;
        const int j0  = kv0 & 7;            // 0 or 4
#pragma unroll
        for (int k = 0; k < 4; ++k) {
            const int d    = d0 + k;
            const int lanev = (d & 31) + 32 * hiv;
            short4v w;
            w[0] = f2bf(r0[k]); w[1] = f2bf(r1[k]);
            w[2] = f2bf(r2[k]); w[3] = f2bf(r3[k]);
            *reinterpret_cast<short4v*>(
                vt + (((d >> 5) * 4 + ks) * 64 + lanev) * 8 + j0) = w;
        }
    }
}

// ------------- attn: 8 waves = 4 qsub(32 q-rows) x 2 KV halves --------------
__global__ __launch_bounds__(512) void attn_fwd_kernel(
    const float* __restrict__ Q,
    const short* __restrict__ Kf,
    const short* __restrict__ Vf,
    const int* __restrict__ valid_lens,
    float* __restrict__ O)
{
    __shared__ float  mrg[4][2048];        // halves merge (32 KB)
    __shared__ float2 mlb[4][32];

    const int tid  = threadIdx.x;
    const int wave = tid >> 6;
    const int lane = tid & 63;
    const int l31  = lane & 31;
    const int hi   = lane >> 5;
    const int h    = wave >> 2;            // KV half
    const int qsub = wave & 3;             // q sub-tile (32 rows)

    const int b  = blockIdx.x & 15;        // batch's 16 blocks -> same XCD L2
    const int qt = blockIdx.x >> 4;
    const int qbase = qt * 128 + qsub * 32;

    const int vlen  = valid_lens[b];
    const int nkv   = (vlen == 0) ? NKV : vlen;
    const int tiles = (nkv + KVB - 1) / KVB;
    const int nh = (tiles + 1 - h) >> 1;   // my half's tiles (interleaved)

    // Q B-fragments (scale folded): lane col q=l31, k-elems d = kk*16+hi*8+j
    const float* Qb = Q + ((size_t)b * NQ + qbase + l31) * DH;
    short8 qfrag[4];
#pragma unroll
    for (int kk = 0; kk < 4; ++kk) {
        const float* p = Qb + kk * 16 + hi * 8;
        float4v a = *reinterpret_cast<const float4v*>(p);
        float4v c = *reinterpret_cast<const float4v*>(p + 4);
#pragma unroll
        for (int j = 0; j < 4; ++j) { a[j] *= SCALE_LOG2; c[j] *= SCALE_LOG2; }
        qfrag[kk] = cvt8(a, c);
    }

    const short* Kfb = Kf + (size_t)b * NTILES * TILE_ELEMS + lane * 8;
    const short* Vfb = Vf + (size_t)b * NTILES * TILE_ELEMS + lane * 8;

    auto load_k = [&](short8 (&kf)[8], int k) {   // k-th tile of my half
        const short* p = Kfb + (size_t)(2 * k + h) * TILE_ELEMS;
#pragma unroll
        for (int i = 0; i < 8; ++i)
            kf[i] = *reinterpret_cast<const short8*>(p + i * 512);
    };

    f32x16 acc_oA[2], acc_oB[2];
#pragma unroll
    for (int t = 0; t < 2; ++t)
#pragma unroll
        for (int r = 0; r < 16; ++r) { acc_oA[t][r] = 0.f; acc_oB[t][r] = 0.f; }
    float m = -INFINITY, lsum = 0.f;

    short8 kfA[8], kfB[8];
    f32x16 sA[2], sB[2];                   // pipelined QK^T score sets

    // QK^T for one tile: pure MFMA, independent of everything but kf/qfrag
    auto qkt = [&](short8 (&kc)[8], f32x16 (&s)[2]) {
#pragma unroll
        for (int ss = 0; ss < 2; ++ss)
#pragma unroll
            for (int r = 0; r < 16; ++r) s[ss][r] = 0.f;
        __builtin_amdgcn_s_setprio(1);
#pragma unroll
        for (int ss = 0; ss < 2; ++ss)
#pragma unroll
            for (int kk = 0; kk < 4; ++kk)
                s[ss] = __builtin_amdgcn_mfma_f32_32x32x16_bf16(
                    kc[ss * 4 + kk], qfrag[kk], s[ss], 0, 0, 0);
        __builtin_amdgcn_s_setprio(0);
    };

    // softmax + PV for one tile whose scores are ready in s
    auto soft_pv = [&](f32x16 (&s)[2], f32x16 (&am)[2], int k) {
        const int tile = 2 * k + h;

        short8 vfr[8];                     // V fragments, loaded early
        {
            const short* p = Vfb + (size_t)tile * TILE_ELEMS;
#pragma unroll
            for (int i = 0; i < 8; ++i)
                vfr[i] = *reinterpret_cast<const short8*>(p + i * 512);
        }

        // ---- mask, skipped for fully-valid tiles (wave-uniform) ----
        if (vlen < (tile + 1) * KVB) {
            const int kvb0 = tile * KVB + 4 * hi;
#pragma unroll
            for (int ss = 0; ss < 2; ++ss) {
                const int vlim = vlen - (kvb0 + ss * 32);
#pragma unroll
                for (int r = 0; r < 16; ++r) {
                    const int rc = (r & 3) + 8 * (r >> 2);
                    s[ss][r] = (rc < vlim) ? s[ss][r] : NEG_INF;
                }
            }
        }

        // ---- row max: depth-5 tree + 1 shuffle ----
        float mx[8];
#pragma unroll
        for (int r = 0; r < 8; ++r)
            mx[r] = fmaxf(fmaxf(s[0][r], s[0][r + 8]),
                          fmaxf(s[1][r], s[1][r + 8]));
#pragma unroll
        for (int d = 4; d; d >>= 1)
#pragma unroll
            for (int r = 0; r < d; ++r) mx[r] = fmaxf(mx[r], mx[r + d]);
        float xv = mx[0];
        xv = fmaxf(xv, __shfl_xor(xv, 32, 64));

        // ---- T13 defer-max (rescale BOTH accumulator sets; rare) ----
        float mn = m;
        if (!__all(xv <= m + 8.f)) {
            mn = fmaxf(m, xv);
            const float alpha = fexp2(m - mn);   // m=-inf first -> 0
            m = mn;
            lsum *= alpha;
#pragma unroll
            for (int r = 0; r < 16; ++r) {
                const int rc = (r & 3) + 8 * (r >> 2);
                const float ar = __shfl(alpha, rc + 4 * hi, 64);
                acc_oA[0][r] *= ar; acc_oA[1][r] *= ar;
                acc_oB[0][r] *= ar; acc_oB[1][r] *= ar;
            }
        }

        // ---- P = 2^(s - mn); sum as tree + 1 shuffle ----
#pragma unroll
        for (int ss = 0; ss < 2; ++ss)
#pragma unroll
            for (int r = 0; r < 16; ++r) s[ss][r] = fexp2(s[ss][r] - mn);
        float sm[8];
#pragma unroll
        for (int r = 0; r < 8; ++r)
            sm[r] = (s[0][r] + s[0][r + 8]) + (s[1][r] + s[1][r + 8]);
#pragma unroll
        for (int d = 4; d; d >>= 1)
#pragma unroll
            for (int r = 0; r < d; ++r) sm[r] += sm[r + d];
        float rs = sm[0];
        rs += __shfl_xor(rs, 32, 64);
        lsum += rs;

        // ---- P -> bf16 packs (16 cvt_pk) ----
        unsigned pk[2][4][2];
#pragma unroll
        for (int ss = 0; ss < 2; ++ss)
#pragma unroll
            for (int be = 0; be < 4; ++be)
#pragma unroll
                for (int c = 0; c < 2; ++c)
                    asm("v_cvt_pk_bf16_f32 %0, %1, %2"
                        : "=v"(pk[ss][be][c])
                        : "v"(s[ss][4 * be + 2 * c]),
                          "v"(s[ss][4 * be + 2 * c + 1]));

        // ---- O(me) += P V: 8 permlane32_swap build A-frags in-register ----
        __builtin_amdgcn_s_setprio(1);
#pragma unroll
        for (int ks = 0; ks < 4; ++ks) {
            const int ss = ks >> 1, g = ks & 1;
            unsigned w0 = pk[ss][2 * g][0], w2 = pk[ss][2 * g + 1][0];
            unsigned w1 = pk[ss][2 * g][1], w3 = pk[ss][2 * g + 1][1];
            asm("v_permlane32_swap_b32 %0, %1" : "+v"(w0), "+v"(w2));
            asm("v_permlane32_swap_b32 %0, %1" : "+v"(w1), "+v"(w3));
            union { unsigned u[4]; short8 s8; } pf;
            pf.u[0] = w0; pf.u[1] = w1; pf.u[2] = w2; pf.u[3] = w3;
#pragma unroll
            for (int t = 0; t < 2; ++t)
                am[t] = __builtin_amdgcn_mfma_f32_32x32x16_bf16(
                    pf.s8, vfr[t * 4 + ks], am[t], 0, 0, 0);
        }
        __builtin_amdgcn_s_setprio(0);
    };

    // ---- pipelined main loop: scores for k+1 computed before PV of k ----
    if (nh > 0) { load_k(kfA, 0); qkt(kfA, sA); }
    if (nh > 1) load_k(kfB, 1);
    int it = 0;
    for (; it + 1 < nh; it += 2) {
        // even body: consume sA (tile it); produce sB (tile it+1)
        qkt(kfB, sB);                      // MFMA overlaps soft_pv's VALU
        if (it + 2 < nh) load_k(kfA, it + 2);
        soft_pv(sA, acc_oA, it);
        // odd body: consume sB (tile it+1); produce sA (tile it+2)
        if (it + 2 < nh) {
            qkt(kfA, sA);
            if (it + 3 < nh) load_k(kfB, it + 3);
        }
        soft_pv(sB, acc_oB, it + 1);
    }
    if (it < nh) soft_pv(sA, acc_oA, it);  // odd-count tail (scores ready)

    // combine the two chains (same scale)
#pragma unroll
    for (int t = 0; t < 2; ++t)
#pragma unroll
        for (int r = 0; r < 16; ++r) acc_oA[t][r] += acc_oB[t][r];

    // ---- merge the two KV halves; h==0 writes output ----
    if (h == 1) {
#pragma unroll
        for (int t = 0; t < 2; ++t)
#pragma unroll
            for (int r = 0; r < 16; ++r)
                mrg[qsub][(t * 16 + r) * 64 + lane] = acc_oA[t][r];
        if (lane < 32) mlb[qsub][lane] = float2{m, lsum};
    }
    __syncthreads();
    if (h == 0) {
        const float2 o1 = mlb[qsub][l31];
        const float m1 = o1.x, l1 = o1.y;
        const float M  = (l1 > 0.f) ? fmaxf(m, m1) : m;
        const float w0 = fexp2(m - M);
        const float w1 = (l1 > 0.f) ? fexp2(m1 - M) : 0.f;
        const float L  = lsum * w0 + l1 * w1;
        const float a0 = w0 / L, a1 = w1 / L;
        float* Ob = O + ((size_t)b * NQ + qbase) * DH;
#pragma unroll
        for (int r = 0; r < 16; ++r) {
            const int rc = (r & 3) + 8 * (r >> 2);
            const float a0r = __shfl(a0, rc + 4 * hi, 64);
            const float a1r = __shfl(a1, rc + 4 * hi, 64);
#pragma unroll
            for (int t = 0; t < 2; ++t) {
                const float oh = mrg[qsub][(t * 16 + r) * 64 + lane];
                Ob[(size_t)(rc + 4 * hi) * DH + t * 32 + l31] =
                    acc_oA[t][r] * a0r + oh * a1r;
            }
        }
    }
}

extern "C" void kernel_launch(void* const* d_in, const int* in_sizes, int n_in,
                              void* d_out, int out_size, void* d_ws, size_t ws_size,
                              hipStream_t stream) {
    const float* Q = (const float*)d_in[0];
    const float* K = (const float*)d_in[1];
    const float* V = (const float*)d_in[2];
    const int* vl  = (const int*)d_in[3];
    float* Out     = (float*)d_out;

    short* Kws = (short*)d_ws;
    short* Vws = Kws + (size_t)BATCH * NTILES * TILE_ELEMS;

    prep_kernel<<<dim3(BATCH * NTILES), dim3(256), 0, stream>>>(K, V, vl, Kws, Vws);
    attn_fwd_kernel<<<dim3(BATCH * (NQ / 128)), dim3(512), 0, stream>>>(
        Q, Kws, Vws, vl, Out);
}

// Round 17
// 48.434 us; speedup vs baseline: 3.9214x; 1.0010x over previous
//
#include <hip/hip_runtime.h>
#include <hip/hip_bf16.h>

// Masked SDPA, B=16, NQ=2048, NKV=2048, D=64, f32 in/out, bf16 MFMA compute.
// R17 = R16 + __launch_bounds__(512, 2) on the attn kernel. R16's pipeline
// state (sA/sB score sets + double K buffer, ~100 extra VGPRs) spilled to
// scratch (WRITE_SIZE 21.5MB vs 8MB output) because the compiler targeted
// 4 waves/SIMD (128 VGPR); our grid is 1 block/CU = 2 waves/SIMD regardless,
// so capping min-waves at 2 unlocks 256 VGPR at zero occupancy cost.
// Everything else byte-identical to R16: 1-tile-ahead QK^T pipeline (MFMA of
// tile t+1 overlaps softmax VALU of tile t), chain-split A/B accumulators,
// reg-direct fragment loads, swapped 32x32 QK^T, in-reg P (cvt_pk +
// permlane32_swap), T13 defer-max, raw v_exp_f32, LDS merge epilogue.

typedef __attribute__((ext_vector_type(8))) short short8;
typedef __attribute__((ext_vector_type(4))) short short4v;
typedef __attribute__((ext_vector_type(4))) float float4v;
typedef __attribute__((ext_vector_type(16))) float f32x16;

#define BATCH 16
#define NQ 2048
#define NKV 2048
#define DH 64
#define KVB 64
#define NTILES (NKV / KVB)          // 32
#define TILE_ELEMS (KVB * DH)       // 4096 bf16 = 8 KB per tile per array
#define NEG_INF -1e20f
// (1/sqrt(64)) * log2(e)
#define SCALE_LOG2 0.180336880111120f

__device__ __forceinline__ short f2bf(float x) {
    union { float f; unsigned u; } v; v.f = x;
    unsigned r = (v.u + 0x7fffu + ((v.u >> 16) & 1u)) >> 16;
    return (short)r;
}

__device__ __forceinline__ short8 cvt8(float4v a, float4v b) {
    short8 r;
    r[0] = f2bf(a[0]); r[1] = f2bf(a[1]); r[2] = f2bf(a[2]); r[3] = f2bf(a[3]);
    r[4] = f2bf(b[0]); r[5] = f2bf(b[1]); r[6] = f2bf(b[2]); r[7] = f2bf(b[3]);
    return r;
}

__device__ __forceinline__ float fexp2(float x) {
    float r; asm("v_exp_f32 %0, %1" : "=v"(r) : "v"(x)); return r;
}

// ---- prep: f32 -> bf16 fragment-sequential layouts (unchanged) -------------
__global__ __launch_bounds__(256) void prep_kernel(
    const float* __restrict__ K, const float* __restrict__ V,
    const int* __restrict__ valid_lens,
    short* __restrict__ Kf, short* __restrict__ Vf)
{
    const int b    = blockIdx.x >> 5;
    const int tile = blockIdx.x & 31;
    const int vlen = valid_lens[b];
    const int nkv  = (vlen == 0) ? NKV : vlen;
    if (tile * KVB >= nkv) return;          // never read by attn

    const int tid = threadIdx.x;
    const int ln  = tid & 63;
    const int l31 = ln & 31;
    const int hi8 = (ln >> 5) * 8;
    const size_t gbase = ((size_t)b * NKV + (size_t)tile * KVB) * DH;
    short* kt = Kf + (((size_t)b * NTILES + tile) * TILE_ELEMS);
    short* vt = Vf + (((size_t)b * NTILES + tile) * TILE_ELEMS);

#pragma unroll
    for (int s = 0; s < 2; ++s) {           // K frags: slots s*256+tid
        const int kk = tid >> 6;            // 0..3
        const int kv = s * 32 + l31;
        const int d  = kk * 16 + hi8;
        const float* p = K + gbase + (size_t)kv * DH + d;
        *reinterpret_cast<short8*>(kt + (s * 256 + tid) * 8) =
            cvt8(*reinterpret_cast<const float4v*>(p),
                 *reinterpret_cast<const float4v*>(p + 4));
    }
    {   // V: 4x4 float4 transpose -> short4 writes into frag-sequential layout
        const int kv0 = (tid >> 4) << 2;    // 0..60 step 4
        const int d0  = (tid & 15) << 2;    // 0..60 step 4
        const float* p = V + gbase + (size_t)kv0 * DH + d0;
        float4v r0 = *reinterpret_cast<const float4v*>(p);
        float4v r1 = *reinterpret_cast<const float4v*>(p + DH);
        float4v r2 = *reinterpret_cast<const float4v*>(p + 2 * DH);
        float4v r3 = *reinterpret_cast<const float4v*>(p + 3 * DH);
        const int ks  = kv0 >> 4;
        const int hiv = (kv0 >> 3) & 1;
        const int j0  = kv0 & 7;            // 0 or 4
#pragma unroll
        for (int k = 0; k < 4; ++k) {
            const int d    = d0 + k;
            const int lanev = (d & 31) + 32 * hiv;
            short4v w;
            w[0] = f2bf(r0[k]); w[1] = f2bf(r1[k]);
            w[2] = f2bf(r2[k]); w[3] = f2bf(r3[k]);
            *reinterpret_cast<short4v*>(
                vt + (((d >> 5) * 4 + ks) * 64 + lanev) * 8 + j0) = w;
        }
    }
}

// ------------- attn: 8 waves = 4 qsub(32 q-rows) x 2 KV halves --------------
__global__ __launch_bounds__(512, 2) void attn_fwd_kernel(
    const float* __restrict__ Q,
    const short* __restrict__ Kf,
    const short* __restrict__ Vf,
    const int* __restrict__ valid_lens,
    float* __restrict__ O)
{
    __shared__ float  mrg[4][2048];        // halves merge (32 KB)
    __shared__ float2 mlb[4][32];

    const int tid  = threadIdx.x;
    const int wave = tid >> 6;
    const int lane = tid & 63;
    const int l31  = lane & 31;
    const int hi   = lane >> 5;
    const int h    = wave >> 2;            // KV half
    const int qsub = wave & 3;             // q sub-tile (32 rows)

    const int b  = blockIdx.x & 15;        // batch's 16 blocks -> same XCD L2
    const int qt = blockIdx.x >> 4;
    const int qbase = qt * 128 + qsub * 32;

    const int vlen  = valid_lens[b];
    const int nkv   = (vlen == 0) ? NKV : vlen;
    const int tiles = (nkv + KVB - 1) / KVB;
    const int nh = (tiles + 1 - h) >> 1;   // my half's tiles (interleaved)

    // Q B-fragments (scale folded): lane col q=l31, k-elems d = kk*16+hi*8+j
    const float* Qb = Q + ((size_t)b * NQ + qbase + l31) * DH;
    short8 qfrag[4];
#pragma unroll
    for (int kk = 0; kk < 4; ++kk) {
        const float* p = Qb + kk * 16 + hi * 8;
        float4v a = *reinterpret_cast<const float4v*>(p);
        float4v c = *reinterpret_cast<const float4v*>(p + 4);
#pragma unroll
        for (int j = 0; j < 4; ++j) { a[j] *= SCALE_LOG2; c[j] *= SCALE_LOG2; }
        qfrag[kk] = cvt8(a, c);
    }

    const short* Kfb = Kf + (size_t)b * NTILES * TILE_ELEMS + lane * 8;
    const short* Vfb = Vf + (size_t)b * NTILES * TILE_ELEMS + lane * 8;

    auto load_k = [&](short8 (&kf)[8], int k) {   // k-th tile of my half
        const short* p = Kfb + (size_t)(2 * k + h) * TILE_ELEMS;
#pragma unroll
        for (int i = 0; i < 8; ++i)
            kf[i] = *reinterpret_cast<const short8*>(p + i * 512);
    };

    f32x16 acc_oA[2], acc_oB[2];
#pragma unroll
    for (int t = 0; t < 2; ++t)
#pragma unroll
        for (int r = 0; r < 16; ++r) { acc_oA[t][r] = 0.f; acc_oB[t][r] = 0.f; }
    float m = -INFINITY, lsum = 0.f;

    short8 kfA[8], kfB[8];
    f32x16 sA[2], sB[2];                   // pipelined QK^T score sets

    // QK^T for one tile: pure MFMA, independent of everything but kf/qfrag
    auto qkt = [&](short8 (&kc)[8], f32x16 (&s)[2]) {
#pragma unroll
        for (int ss = 0; ss < 2; ++ss)
#pragma unroll
            for (int r = 0; r < 16; ++r) s[ss][r] = 0.f;
        __builtin_amdgcn_s_setprio(1);
#pragma unroll
        for (int ss = 0; ss < 2; ++ss)
#pragma unroll
            for (int kk = 0; kk < 4; ++kk)
                s[ss] = __builtin_amdgcn_mfma_f32_32x32x16_bf16(
                    kc[ss * 4 + kk], qfrag[kk], s[ss], 0, 0, 0);
        __builtin_amdgcn_s_setprio(0);
    };

    // softmax + PV for one tile whose scores are ready in s
    auto soft_pv = [&](f32x16 (&s)[2], f32x16 (&am)[2], int k) {
        const int tile = 2 * k + h;

        short8 vfr[8];                     // V fragments, loaded early
        {
            const short* p = Vfb + (size_t)tile * TILE_ELEMS;
#pragma unroll
            for (int i = 0; i < 8; ++i)
                vfr[i] = *reinterpret_cast<const short8*>(p + i * 512);
        }

        // ---- mask, skipped for fully-valid tiles (wave-uniform) ----
        if (vlen < (tile + 1) * KVB) {
            const int kvb0 = tile * KVB + 4 * hi;
#pragma unroll
            for (int ss = 0; ss < 2; ++ss) {
                const int vlim = vlen - (kvb0 + ss * 32);
#pragma unroll
                for (int r = 0; r < 16; ++r) {
                    const int rc = (r & 3) + 8 * (r >> 2);
                    s[ss][r] = (rc < vlim) ? s[ss][r] : NEG_INF;
                }
            }
        }

        // ---- row max: depth-5 tree + 1 shuffle ----
        float mx[8];
#pragma unroll
        for (int r = 0; r < 8; ++r)
            mx[r] = fmaxf(fmaxf(s[0][r], s[0][r + 8]),
                          fmaxf(s[1][r], s[1][r + 8]));
#pragma unroll
        for (int d = 4; d; d >>= 1)
#pragma unroll
            for (int r = 0; r < d; ++r) mx[r] = fmaxf(mx[r], mx[r + d]);
        float xv = mx[0];
        xv = fmaxf(xv, __shfl_xor(xv, 32, 64));

        // ---- T13 defer-max (rescale BOTH accumulator sets; rare) ----
        float mn = m;
        if (!__all(xv <= m + 8.f)) {
            mn = fmaxf(m, xv);
            const float alpha = fexp2(m - mn);   // m=-inf first -> 0
            m = mn;
            lsum *= alpha;
#pragma unroll
            for (int r = 0; r < 16; ++r) {
                const int rc = (r & 3) + 8 * (r >> 2);
                const float ar = __shfl(alpha, rc + 4 * hi, 64);
                acc_oA[0][r] *= ar; acc_oA[1][r] *= ar;
                acc_oB[0][r] *= ar; acc_oB[1][r] *= ar;
            }
        }

        // ---- P = 2^(s - mn); sum as tree + 1 shuffle ----
#pragma unroll
        for (int ss = 0; ss < 2; ++ss)
#pragma unroll
            for (int r = 0; r < 16; ++r) s[ss][r] = fexp2(s[ss][r] - mn);
        float sm[8];
#pragma unroll
        for (int r = 0; r < 8; ++r)
            sm[r] = (s[0][r] + s[0][r + 8]) + (s[1][r] + s[1][r + 8]);
#pragma unroll
        for (int d = 4; d; d >>= 1)
#pragma unroll
            for (int r = 0; r < d; ++r) sm[r] += sm[r + d];
        float rs = sm[0];
        rs += __shfl_xor(rs, 32, 64);
        lsum += rs;

        // ---- P -> bf16 packs (16 cvt_pk) ----
        unsigned pk[2][4][2];
#pragma unroll
        for (int ss = 0; ss < 2; ++ss)
#pragma unroll
            for (int be = 0; be < 4; ++be)
#pragma unroll
                for (int c = 0; c < 2; ++c)
                    asm("v_cvt_pk_bf16_f32 %0, %1, %2"
                        : "=v"(pk[ss][be][c])
                        : "v"(s[ss][4 * be + 2 * c]),
                          "v"(s[ss][4 * be + 2 * c + 1]));

        // ---- O(me) += P V: 8 permlane32_swap build A-frags in-register ----
        __builtin_amdgcn_s_setprio(1);
#pragma unroll
        for (int ks = 0; ks < 4; ++ks) {
            const int ss = ks >> 1, g = ks & 1;
            unsigned w0 = pk[ss][2 * g][0], w2 = pk[ss][2 * g + 1][0];
            unsigned w1 = pk[ss][2 * g][1], w3 = pk[ss][2 * g + 1][1];
            asm("v_permlane32_swap_b32 %0, %1" : "+v"(w0), "+v"(w2));
            asm("v_permlane32_swap_b32 %0, %1" : "+v"(w1), "+v"(w3));
            union { unsigned u[4]; short8 s8; } pf;
            pf.u[0] = w0; pf.u[1] = w1; pf.u[2] = w2; pf.u[3] = w3;
#pragma unroll
            for (int t = 0; t < 2; ++t)
                am[t] = __builtin_amdgcn_mfma_f32_32x32x16_bf16(
                    pf.s8, vfr[t * 4 + ks], am[t], 0, 0, 0);
        }
        __builtin_amdgcn_s_setprio(0);
    };

    // ---- pipelined main loop: scores for k+1 computed before PV of k ----
    if (nh > 0) { load_k(kfA, 0); qkt(kfA, sA); }
    if (nh > 1) load_k(kfB, 1);
    int it = 0;
    for (; it + 1 < nh; it += 2) {
        // even body: consume sA (tile it); produce sB (tile it+1)
        qkt(kfB, sB);                      // MFMA overlaps soft_pv's VALU
        if (it + 2 < nh) load_k(kfA, it + 2);
        soft_pv(sA, acc_oA, it);
        // odd body: consume sB (tile it+1); produce sA (tile it+2)
        if (it + 2 < nh) {
            qkt(kfA, sA);
            if (it + 3 < nh) load_k(kfB, it + 3);
        }
        soft_pv(sB, acc_oB, it + 1);
    }
    if (it < nh) soft_pv(sA, acc_oA, it);  // odd-count tail (scores ready)

    // combine the two chains (same scale)
#pragma unroll
    for (int t = 0; t < 2; ++t)
#pragma unroll
        for (int r = 0; r < 16; ++r) acc_oA[t][r] += acc_oB[t][r];

    // ---- merge the two KV halves; h==0 writes output ----
    if (h == 1) {
#pragma unroll
        for (int t = 0; t < 2; ++t)
#pragma unroll
            for (int r = 0; r < 16; ++r)
                mrg[qsub][(t * 16 + r) * 64 + lane] = acc_oA[t][r];
        if (lane < 32) mlb[qsub][lane] = float2{m, lsum};
    }
    __syncthreads();
    if (h == 0) {
        const float2 o1 = mlb[qsub][l31];
        const float m1 = o1.x, l1 = o1.y;
        const float M  = (l1 > 0.f) ? fmaxf(m, m1) : m;
        const float w0 = fexp2(m - M);
        const float w1 = (l1 > 0.f) ? fexp2(m1 - M) : 0.f;
        const float L  = lsum * w0 + l1 * w1;
        const float a0 = w0 / L, a1 = w1 / L;
        float* Ob = O + ((size_t)b * NQ + qbase) * DH;
#pragma unroll
        for (int r = 0; r < 16; ++r) {
            const int rc = (r & 3) + 8 * (r >> 2);
            const float a0r = __shfl(a0, rc + 4 * hi, 64);
            const float a1r = __shfl(a1, rc + 4 * hi, 64);
#pragma unroll
            for (int t = 0; t < 2; ++t) {
                const float oh = mrg[qsub][(t * 16 + r) * 64 + lane];
                Ob[(size_t)(rc + 4 * hi) * DH + t * 32 + l31] =
                    acc_oA[t][r] * a0r + oh * a1r;
            }
        }
    }
}

extern "C" void kernel_launch(void* const* d_in, const int* in_sizes, int n_in,
                              void* d_out, int out_size, void* d_ws, size_t ws_size,
                              hipStream_t stream) {
    const float* Q = (const float*)d_in[0];
    const float* K = (const float*)d_in[1];
    const float* V = (const float*)d_in[2];
    const int* vl  = (const int*)d_in[3];
    float* Out     = (float*)d_out;

    short* Kws = (short*)d_ws;
    short* Vws = Kws + (size_t)BATCH * NTILES * TILE_ELEMS;

    prep_kernel<<<dim3(BATCH * NTILES), dim3(256), 0, stream>>>(K, V, vl, Kws, Vws);
    attn_fwd_kernel<<<dim3(BATCH * (NQ / 128)), dim3(512), 0, stream>>>(
        Q, Kws, Vws, vl, Out);
}

// Round 18
// 37.012 us; speedup vs baseline: 5.1316x; 1.3086x over previous
//
#include <hip/hip_runtime.h>
#include <hip/hip_bf16.h>

// Masked SDPA, B=16, NQ=2048, NKV=2048, D=64, f32 in/out, bf16 MFMA compute.
// R18 = R16/R17 pipeline with the occupancy knob that actually works:
//   __attribute__((amdgpu_waves_per_eu(2,2))) pins the register allocator's
//   target to 2 waves/EU -> 256 VGPR budget (launch_bounds' min-only hint in
//   R17 changed nothing: identical VGPR=128 + 21MB scratch spill).
//   Plus: single K fragment buffer (reload after qkt consumes it; soft_pv
//   covers the L2 latency) -> peak live set ~225 regs, fits under 256.
// Pipeline: QK^T(t+1) (pure MFMA) issues between softmax(t) (VALU) and PV(t)
// -> MFMA and VALU pipes overlap across tiles. Everything else from R13:
// chain-split A/B accumulators, reg-direct fragment loads from ws, swapped
// 32x32 QK^T, in-reg P (cvt_pk+permlane32_swap), T13 defer-max, raw
// v_exp_f32, LDS merge epilogue. No cross-block fences/atomics (R15 lesson).

typedef __attribute__((ext_vector_type(8))) short short8;
typedef __attribute__((ext_vector_type(4))) short short4v;
typedef __attribute__((ext_vector_type(4))) float float4v;
typedef __attribute__((ext_vector_type(16))) float f32x16;

#define BATCH 16
#define NQ 2048
#define NKV 2048
#define DH 64
#define KVB 64
#define NTILES (NKV / KVB)          // 32
#define TILE_ELEMS (KVB * DH)       // 4096 bf16 = 8 KB per tile per array
#define NEG_INF -1e20f
// (1/sqrt(64)) * log2(e)
#define SCALE_LOG2 0.180336880111120f

__device__ __forceinline__ short f2bf(float x) {
    union { float f; unsigned u; } v; v.f = x;
    unsigned r = (v.u + 0x7fffu + ((v.u >> 16) & 1u)) >> 16;
    return (short)r;
}

__device__ __forceinline__ short8 cvt8(float4v a, float4v b) {
    short8 r;
    r[0] = f2bf(a[0]); r[1] = f2bf(a[1]); r[2] = f2bf(a[2]); r[3] = f2bf(a[3]);
    r[4] = f2bf(b[0]); r[5] = f2bf(b[1]); r[6] = f2bf(b[2]); r[7] = f2bf(b[3]);
    return r;
}

__device__ __forceinline__ float fexp2(float x) {
    float r; asm("v_exp_f32 %0, %1" : "=v"(r) : "v"(x)); return r;
}

// ---- prep: f32 -> bf16 fragment-sequential layouts (unchanged) -------------
__global__ __launch_bounds__(256) void prep_kernel(
    const float* __restrict__ K, const float* __restrict__ V,
    const int* __restrict__ valid_lens,
    short* __restrict__ Kf, short* __restrict__ Vf)
{
    const int b    = blockIdx.x >> 5;
    const int tile = blockIdx.x & 31;
    const int vlen = valid_lens[b];
    const int nkv  = (vlen == 0) ? NKV : vlen;
    if (tile * KVB >= nkv) return;          // never read by attn

    const int tid = threadIdx.x;
    const int ln  = tid & 63;
    const int l31 = ln & 31;
    const int hi8 = (ln >> 5) * 8;
    const size_t gbase = ((size_t)b * NKV + (size_t)tile * KVB) * DH;
    short* kt = Kf + (((size_t)b * NTILES + tile) * TILE_ELEMS);
    short* vt = Vf + (((size_t)b * NTILES + tile) * TILE_ELEMS);

#pragma unroll
    for (int s = 0; s < 2; ++s) {           // K frags: slots s*256+tid
        const int kk = tid >> 6;            // 0..3
        const int kv = s * 32 + l31;
        const int d  = kk * 16 + hi8;
        const float* p = K + gbase + (size_t)kv * DH + d;
        *reinterpret_cast<short8*>(kt + (s * 256 + tid) * 8) =
            cvt8(*reinterpret_cast<const float4v*>(p),
                 *reinterpret_cast<const float4v*>(p + 4));
    }
    {   // V: 4x4 float4 transpose -> short4 writes into frag-sequential layout
        const int kv0 = (tid >> 4) << 2;    // 0..60 step 4
        const int d0  = (tid & 15) << 2;    // 0..60 step 4
        const float* p = V + gbase + (size_t)kv0 * DH + d0;
        float4v r0 = *reinterpret_cast<const float4v*>(p);
        float4v r1 = *reinterpret_cast<const float4v*>(p + DH);
        float4v r2 = *reinterpret_cast<const float4v*>(p + 2 * DH);
        float4v r3 = *reinterpret_cast<const float4v*>(p + 3 * DH);
        const int ks  = kv0 >> 4;
        const int hiv = (kv0 >> 3) & 1;
        const int j0  = kv0 & 7;            // 0 or 4
#pragma unroll
        for (int k = 0; k < 4; ++k) {
            const int d    = d0 + k;
            const int lanev = (d & 31) + 32 * hiv;
            short4v w;
            w[0] = f2bf(r0[k]); w[1] = f2bf(r1[k]);
            w[2] = f2bf(r2[k]); w[3] = f2bf(r3[k]);
            *reinterpret_cast<short4v*>(
                vt + (((d >> 5) * 4 + ks) * 64 + lanev) * 8 + j0) = w;
        }
    }
}

// ------------- attn: 8 waves = 4 qsub(32 q-rows) x 2 KV halves --------------
__global__
__attribute__((amdgpu_flat_work_group_size(512, 512), amdgpu_waves_per_eu(2, 2)))
void attn_fwd_kernel(
    const float* __restrict__ Q,
    const short* __restrict__ Kf,
    const short* __restrict__ Vf,
    const int* __restrict__ valid_lens,
    float* __restrict__ O)
{
    __shared__ float  mrg[4][2048];        // halves merge (32 KB)
    __shared__ float2 mlb[4][32];

    const int tid  = threadIdx.x;
    const int wave = tid >> 6;
    const int lane = tid & 63;
    const int l31  = lane & 31;
    const int hi   = lane >> 5;
    const int h    = wave >> 2;            // KV half
    const int qsub = wave & 3;             // q sub-tile (32 rows)

    const int b  = blockIdx.x & 15;        // batch's 16 blocks -> same XCD L2
    const int qt = blockIdx.x >> 4;
    const int qbase = qt * 128 + qsub * 32;

    const int vlen  = valid_lens[b];
    const int nkv   = (vlen == 0) ? NKV : vlen;
    const int tiles = (nkv + KVB - 1) / KVB;
    const int nh = (tiles + 1 - h) >> 1;   // my half's tiles (interleaved)

    // Q B-fragments (scale folded): lane col q=l31, k-elems d = kk*16+hi*8+j
    const float* Qb = Q + ((size_t)b * NQ + qbase + l31) * DH;
    short8 qfrag[4];
#pragma unroll
    for (int kk = 0; kk < 4; ++kk) {
        const float* p = Qb + kk * 16 + hi * 8;
        float4v a = *reinterpret_cast<const float4v*>(p);
        float4v c = *reinterpret_cast<const float4v*>(p + 4);
#pragma unroll
        for (int j = 0; j < 4; ++j) { a[j] *= SCALE_LOG2; c[j] *= SCALE_LOG2; }
        qfrag[kk] = cvt8(a, c);
    }

    const short* Kfb = Kf + (size_t)b * NTILES * TILE_ELEMS + lane * 8;
    const short* Vfb = Vf + (size_t)b * NTILES * TILE_ELEMS + lane * 8;

    // single K fragment buffer: reloaded right after qkt consumes it
    short8 kf[8];
    auto load_k = [&](int k) {             // k-th tile of my half
        const short* p = Kfb + (size_t)(2 * k + h) * TILE_ELEMS;
#pragma unroll
        for (int i = 0; i < 8; ++i)
            kf[i] = *reinterpret_cast<const short8*>(p + i * 512);
    };

    f32x16 acc_oA[2], acc_oB[2];
#pragma unroll
    for (int t = 0; t < 2; ++t)
#pragma unroll
        for (int r = 0; r < 16; ++r) { acc_oA[t][r] = 0.f; acc_oB[t][r] = 0.f; }
    float m = -INFINITY, lsum = 0.f;

    f32x16 sA[2], sB[2];                   // pipelined QK^T score sets

    // QK^T for one tile: pure MFMA, consumes kf + qfrag
    auto qkt = [&](f32x16 (&s)[2]) {
#pragma unroll
        for (int ss = 0; ss < 2; ++ss)
#pragma unroll
            for (int r = 0; r < 16; ++r) s[ss][r] = 0.f;
        __builtin_amdgcn_s_setprio(1);
#pragma unroll
        for (int ss = 0; ss < 2; ++ss)
#pragma unroll
            for (int kk = 0; kk < 4; ++kk)
                s[ss] = __builtin_amdgcn_mfma_f32_32x32x16_bf16(
                    kf[ss * 4 + kk], qfrag[kk], s[ss], 0, 0, 0);
        __builtin_amdgcn_s_setprio(0);
    };

    // softmax + PV for one tile whose scores are ready in s
    auto soft_pv = [&](f32x16 (&s)[2], f32x16 (&am)[2], int k) {
        const int tile = 2 * k + h;

        short8 vfr[8];                     // V fragments, loaded early
        {
            const short* p = Vfb + (size_t)tile * TILE_ELEMS;
#pragma unroll
            for (int i = 0; i < 8; ++i)
                vfr[i] = *reinterpret_cast<const short8*>(p + i * 512);
        }

        // ---- mask, skipped for fully-valid tiles (wave-uniform) ----
        if (vlen < (tile + 1) * KVB) {
            const int kvb0 = tile * KVB + 4 * hi;
#pragma unroll
            for (int ss = 0; ss < 2; ++ss) {
                const int vlim = vlen - (kvb0 + ss * 32);
#pragma unroll
                for (int r = 0; r < 16; ++r) {
                    const int rc = (r & 3) + 8 * (r >> 2);
                    s[ss][r] = (rc < vlim) ? s[ss][r] : NEG_INF;
                }
            }
        }

        // ---- row max: depth-5 tree + 1 shuffle ----
        float mx[8];
#pragma unroll
        for (int r = 0; r < 8; ++r)
            mx[r] = fmaxf(fmaxf(s[0][r], s[0][r + 8]),
                          fmaxf(s[1][r], s[1][r + 8]));
#pragma unroll
        for (int d = 4; d; d >>= 1)
#pragma unroll
            for (int r = 0; r < d; ++r) mx[r] = fmaxf(mx[r], mx[r + d]);
        float xv = mx[0];
        xv = fmaxf(xv, __shfl_xor(xv, 32, 64));

        // ---- T13 defer-max (rescale BOTH accumulator sets; rare) ----
        float mn = m;
        if (!__all(xv <= m + 8.f)) {
            mn = fmaxf(m, xv);
            const float alpha = fexp2(m - mn);   // m=-inf first -> 0
            m = mn;
            lsum *= alpha;
#pragma unroll
            for (int r = 0; r < 16; ++r) {
                const int rc = (r & 3) + 8 * (r >> 2);
                const float ar = __shfl(alpha, rc + 4 * hi, 64);
                acc_oA[0][r] *= ar; acc_oA[1][r] *= ar;
                acc_oB[0][r] *= ar; acc_oB[1][r] *= ar;
            }
        }

        // ---- P = 2^(s - mn); sum as tree + 1 shuffle ----
#pragma unroll
        for (int ss = 0; ss < 2; ++ss)
#pragma unroll
            for (int r = 0; r < 16; ++r) s[ss][r] = fexp2(s[ss][r] - mn);
        float sm[8];
#pragma unroll
        for (int r = 0; r < 8; ++r)
            sm[r] = (s[0][r] + s[0][r + 8]) + (s[1][r] + s[1][r + 8]);
#pragma unroll
        for (int d = 4; d; d >>= 1)
#pragma unroll
            for (int r = 0; r < d; ++r) sm[r] += sm[r + d];
        float rs = sm[0];
        rs += __shfl_xor(rs, 32, 64);
        lsum += rs;

        // ---- P -> bf16 packs (16 cvt_pk) ----
        unsigned pk[2][4][2];
#pragma unroll
        for (int ss = 0; ss < 2; ++ss)
#pragma unroll
            for (int be = 0; be < 4; ++be)
#pragma unroll
                for (int c = 0; c < 2; ++c)
                    asm("v_cvt_pk_bf16_f32 %0, %1, %2"
                        : "=v"(pk[ss][be][c])
                        : "v"(s[ss][4 * be + 2 * c]),
                          "v"(s[ss][4 * be + 2 * c + 1]));

        // ---- O(me) += P V: 8 permlane32_swap build A-frags in-register ----
        __builtin_amdgcn_s_setprio(1);
#pragma unroll
        for (int ks = 0; ks < 4; ++ks) {
            const int ss = ks >> 1, g = ks & 1;
            unsigned w0 = pk[ss][2 * g][0], w2 = pk[ss][2 * g + 1][0];
            unsigned w1 = pk[ss][2 * g][1], w3 = pk[ss][2 * g + 1][1];
            asm("v_permlane32_swap_b32 %0, %1" : "+v"(w0), "+v"(w2));
            asm("v_permlane32_swap_b32 %0, %1" : "+v"(w1), "+v"(w3));
            union { unsigned u[4]; short8 s8; } pf;
            pf.u[0] = w0; pf.u[1] = w1; pf.u[2] = w2; pf.u[3] = w3;
#pragma unroll
            for (int t = 0; t < 2; ++t)
                am[t] = __builtin_amdgcn_mfma_f32_32x32x16_bf16(
                    pf.s8, vfr[t * 4 + ks], am[t], 0, 0, 0);
        }
        __builtin_amdgcn_s_setprio(0);
    };

    // ---- pipelined main loop: scores for k+1 computed before PV of k ----
    if (nh > 0) { load_k(0); qkt(sA); }
    if (nh > 1) load_k(1);
    int it = 0;
    for (; it + 1 < nh; it += 2) {
        // even body: consume sA (tile it); produce sB (tile it+1)
        qkt(sB);                           // MFMA overlaps soft_pv's VALU
        if (it + 2 < nh) load_k(it + 2);
        soft_pv(sA, acc_oA, it);
        // odd body: consume sB (tile it+1); produce sA (tile it+2)
        if (it + 2 < nh) {
            qkt(sA);
            if (it + 3 < nh) load_k(it + 3);
        }
        soft_pv(sB, acc_oB, it + 1);
    }
    if (it < nh) soft_pv(sA, acc_oA, it);  // odd-count tail (scores ready)

    // combine the two chains (same scale)
#pragma unroll
    for (int t = 0; t < 2; ++t)
#pragma unroll
        for (int r = 0; r < 16; ++r) acc_oA[t][r] += acc_oB[t][r];

    // ---- merge the two KV halves; h==0 writes output ----
    if (h == 1) {
#pragma unroll
        for (int t = 0; t < 2; ++t)
#pragma unroll
            for (int r = 0; r < 16; ++r)
                mrg[qsub][(t * 16 + r) * 64 + lane] = acc_oA[t][r];
        if (lane < 32) mlb[qsub][lane] = float2{m, lsum};
    }
    __syncthreads();
    if (h == 0) {
        const float2 o1 = mlb[qsub][l31];
        const float m1 = o1.x, l1 = o1.y;
        const float M  = (l1 > 0.f) ? fmaxf(m, m1) : m;
        const float w0 = fexp2(m - M);
        const float w1 = (l1 > 0.f) ? fexp2(m1 - M) : 0.f;
        const float L  = lsum * w0 + l1 * w1;
        const float a0 = w0 / L, a1 = w1 / L;
        float* Ob = O + ((size_t)b * NQ + qbase) * DH;
#pragma unroll
        for (int r = 0; r < 16; ++r) {
            const int rc = (r & 3) + 8 * (r >> 2);
            const float a0r = __shfl(a0, rc + 4 * hi, 64);
            const float a1r = __shfl(a1, rc + 4 * hi, 64);
#pragma unroll
            for (int t = 0; t < 2; ++t) {
                const float oh = mrg[qsub][(t * 16 + r) * 64 + lane];
                Ob[(size_t)(rc + 4 * hi) * DH + t * 32 + l31] =
                    acc_oA[t][r] * a0r + oh * a1r;
            }
        }
    }
}

extern "C" void kernel_launch(void* const* d_in, const int* in_sizes, int n_in,
                              void* d_out, int out_size, void* d_ws, size_t ws_size,
                              hipStream_t stream) {
    const float* Q = (const float*)d_in[0];
    const float* K = (const float*)d_in[1];
    const float* V = (const float*)d_in[2];
    const int* vl  = (const int*)d_in[3];
    float* Out     = (float*)d_out;

    short* Kws = (short*)d_ws;
    short* Vws = Kws + (size_t)BATCH * NTILES * TILE_ELEMS;

    prep_kernel<<<dim3(BATCH * NTILES), dim3(256), 0, stream>>>(K, V, vl, Kws, Vws);
    attn_fwd_kernel<<<dim3(BATCH * (NQ / 128)), dim3(512), 0, stream>>>(
        Q, Kws, Vws, vl, Out);
}

// Round 19
// 35.267 us; speedup vs baseline: 5.3855x; 1.0495x over previous
//
#include <hip/hip_runtime.h>
#include <hip/hip_bf16.h>

// Masked SDPA, B=16, NQ=2048, NKV=2048, D=64, f32 in/out, bf16 MFMA compute.
// R19 = R13 body (best, chain-split) x R10 partition (4-way KV split), with
// the three R10 defects fixed:
//  1. chain-split A/B accumulators (R13: -22%/iter vs R10's single chain);
//  2. CU pairing: blocks c and c+256 share a CU; parity=blockIdx>>8 makes
//     them heavy-rank x / light-rank 15-x -> distinct batches, complementary
//     work (R10 had SAME batch on both);
//  3. rank->batch via R15's verified inline wave-parallel ranking (~30
//     instrs; no serial sched kernel (R14), no fences (R15)).
// Shape: grid 512 (2 blocks/CU, all resident), block = 8 waves = 2 qsub(32q)
// x 4 kv-quarters, nh<=8 iters -> 4096 waves = 4 waves/SIMD (2x R13's TLP,
// hiding the ~4500cy per-iter dependency chain). Per XCD: 2 batches = 1MB
// (L2-resident). 4-way padded-LDS merge epilogue (verified in R10).
// R18 lesson: NO explicit cross-tile pipelining (regressed; compiler + wave
// overlap already capture it).

typedef __attribute__((ext_vector_type(8))) short short8;
typedef __attribute__((ext_vector_type(4))) short short4v;
typedef __attribute__((ext_vector_type(4))) float float4v;
typedef __attribute__((ext_vector_type(16))) float f32x16;

#define BATCH 16
#define NQ 2048
#define NKV 2048
#define DH 64
#define KVB 64
#define NTILES (NKV / KVB)          // 32
#define TILE_ELEMS (KVB * DH)       // 4096 bf16 = 8 KB per tile per array
#define NEG_INF -1e20f
// (1/sqrt(64)) * log2(e)
#define SCALE_LOG2 0.180336880111120f

__device__ __forceinline__ short f2bf(float x) {
    union { float f; unsigned u; } v; v.f = x;
    unsigned r = (v.u + 0x7fffu + ((v.u >> 16) & 1u)) >> 16;
    return (short)r;
}

__device__ __forceinline__ short8 cvt8(float4v a, float4v b) {
    short8 r;
    r[0] = f2bf(a[0]); r[1] = f2bf(a[1]); r[2] = f2bf(a[2]); r[3] = f2bf(a[3]);
    r[4] = f2bf(b[0]); r[5] = f2bf(b[1]); r[6] = f2bf(b[2]); r[7] = f2bf(b[3]);
    return r;
}

__device__ __forceinline__ float fexp2(float x) {
    float r; asm("v_exp_f32 %0, %1" : "=v"(r) : "v"(x)); return r;
}

// ---- prep: f32 -> bf16 fragment-sequential layouts (unchanged) -------------
__global__ __launch_bounds__(256) void prep_kernel(
    const float* __restrict__ K, const float* __restrict__ V,
    const int* __restrict__ valid_lens,
    short* __restrict__ Kf, short* __restrict__ Vf)
{
    const int b    = blockIdx.x >> 5;
    const int tile = blockIdx.x & 31;
    const int vlen = valid_lens[b];
    const int nkv  = (vlen == 0) ? NKV : vlen;
    if (tile * KVB >= nkv) return;          // never read by attn

    const int tid = threadIdx.x;
    const int ln  = tid & 63;
    const int l31 = ln & 31;
    const int hi8 = (ln >> 5) * 8;
    const size_t gbase = ((size_t)b * NKV + (size_t)tile * KVB) * DH;
    short* kt = Kf + (((size_t)b * NTILES + tile) * TILE_ELEMS);
    short* vt = Vf + (((size_t)b * NTILES + tile) * TILE_ELEMS);

#pragma unroll
    for (int s = 0; s < 2; ++s) {           // K frags: slots s*256+tid
        const int kk = tid >> 6;            // 0..3
        const int kv = s * 32 + l31;
        const int d  = kk * 16 + hi8;
        const float* p = K + gbase + (size_t)kv * DH + d;
        *reinterpret_cast<short8*>(kt + (s * 256 + tid) * 8) =
            cvt8(*reinterpret_cast<const float4v*>(p),
                 *reinterpret_cast<const float4v*>(p + 4));
    }
    {   // V: 4x4 float4 transpose -> short4 writes into frag-sequential layout
        const int kv0 = (tid >> 4) << 2;    // 0..60 step 4
        const int d0  = (tid & 15) << 2;    // 0..60 step 4
        const float* p = V + gbase + (size_t)kv0 * DH + d0;
        float4v r0 = *reinterpret_cast<const float4v*>(p);
        float4v r1 = *reinterpret_cast<const float4v*>(p + DH);
        float4v r2 = *reinterpret_cast<const float4v*>(p + 2 * DH);
        float4v r3 = *reinterpret_cast<const float4v*>(p + 3 * DH);
        const int ks  = kv0 >> 4;
        const int hiv = (kv0 >> 3) & 1;
        const int j0  = kv0 & 7;            // 0 or 4
#pragma unroll
        for (int k = 0; k < 4; ++k) {
            const int d    = d0 + k;
            const int lanev = (d & 31) + 32 * hiv;
            short4v w;
            w[0] = f2bf(r0[k]); w[1] = f2bf(r1[k]);
            w[2] = f2bf(r2[k]); w[3] = f2bf(r3[k]);
            *reinterpret_cast<short4v*>(
                vt + (((d >> 5) * 4 + ks) * 64 + lanev) * 8 + j0) = w;
        }
    }
}

// --------- attn: 8 waves = 2 qsub(32 q-rows) x 4 KV-quarters ----------------
__global__ __launch_bounds__(512) void attn_fwd_kernel(
    const float* __restrict__ Q,
    const short* __restrict__ Kf,
    const short* __restrict__ Vf,
    const int* __restrict__ vl,
    float* __restrict__ O)
{
    __shared__ float  mrg[2][4][32][68];   // [qsub][kvq][q][d] pad 68 (~69.6KB)
    __shared__ float2 mlb[2][4][32];

    const int tid  = threadIdx.x;
    const int wave = tid >> 6;
    const int lane = tid & 63;
    const int l31  = lane & 31;
    const int hi   = lane >> 5;
    const int qsub = wave >> 2;            // 0..1
    const int kvq  = wave & 3;             // KV quarter

    // ---- block decode: CU c hosts blocks c (parity 0) and c+256 (parity 1)
    const int x      = blockIdx.x & 7;         // XCD (%8 dispatch heuristic)
    const int parity = blockIdx.x >> 8;        // 0: heavy rank, 1: light rank
    const int qt     = (blockIdx.x >> 3) & 31; // 64-q tile
    const int wrank  = parity ? (15 - x) : x;

    // ---- inline rank -> batch (wave-parallel, verified in R15) ----
    int tv;
    {
        const int v  = vl[lane & 15];
        const int nk = (v == 0) ? NKV : v;
        tv = (nk + KVB - 1) >> 6;
    }
    int rank = 0;
#pragma unroll
    for (int j = 0; j < 16; ++j) {
        const int tj = __shfl(tv, j, 64);
        rank += (tj > tv) || (tj == tv && j < (lane & 15));
    }
    const unsigned long long mk = __ballot((lane < 16) && (rank == wrank));
    const int b = __ffsll(mk) - 1;

    const int vlen  = vl[b];
    const int nkv   = (vlen == 0) ? NKV : vlen;
    const int tiles = (nkv + KVB - 1) >> 6;
    const int nh    = (tiles - kvq + 3) >> 2;  // my quarter (stride 4)
    const int qbase = qt * 64 + qsub * 32;

    // Q B-fragments (scale folded): lane col q=l31, k-elems d = kk*16+hi*8+j
    const float* Qb = Q + ((size_t)b * NQ + qbase + l31) * DH;
    short8 qfrag[4];
#pragma unroll
    for (int kk = 0; kk < 4; ++kk) {
        const float* p = Qb + kk * 16 + hi * 8;
        float4v a = *reinterpret_cast<const float4v*>(p);
        float4v c = *reinterpret_cast<const float4v*>(p + 4);
#pragma unroll
        for (int j = 0; j < 4; ++j) { a[j] *= SCALE_LOG2; c[j] *= SCALE_LOG2; }
        qfrag[kk] = cvt8(a, c);
    }

    const short* Kfb = Kf + (size_t)b * NTILES * TILE_ELEMS + lane * 8;
    const short* Vfb = Vf + (size_t)b * NTILES * TILE_ELEMS + lane * 8;

    auto load_k = [&](short8 (&kf)[8], int tile) {
        const short* p = Kfb + (size_t)tile * TILE_ELEMS;
#pragma unroll
        for (int i = 0; i < 8; ++i)
            kf[i] = *reinterpret_cast<const short8*>(p + i * 512);
    };

    f32x16 acc_oA[2], acc_oB[2];
#pragma unroll
    for (int t = 0; t < 2; ++t)
#pragma unroll
        for (int r = 0; r < 16; ++r) { acc_oA[t][r] = 0.f; acc_oB[t][r] = 0.f; }
    float m = -INFINITY, lsum = 0.f;

    short8 kf0[8], kf1[8];

    auto body = [&](short8 (&kc)[8], short8 (&kn)[8], f32x16 (&am)[2], int it) {
        const int tile = 4 * it + kvq;

        short8 vfr[8];                     // body-local V fragments
        {
            const short* p = Vfb + (size_t)tile * TILE_ELEMS;
#pragma unroll
            for (int i = 0; i < 8; ++i)
                vfr[i] = *reinterpret_cast<const short8*>(p + i * 512);
        }

        // ---- S^T = K Q^T: lane owns q=l31, kv = 32s + (r&3)+8(r>>2)+4hi ----
        f32x16 acs[2];
#pragma unroll
        for (int s = 0; s < 2; ++s)
#pragma unroll
            for (int r = 0; r < 16; ++r) acs[s][r] = 0.f;
        __builtin_amdgcn_s_setprio(1);
#pragma unroll
        for (int s = 0; s < 2; ++s)
#pragma unroll
            for (int kk = 0; kk < 4; ++kk)
                acs[s] = __builtin_amdgcn_mfma_f32_32x32x16_bf16(
                    kc[s * 4 + kk], qfrag[kk], acs[s], 0, 0, 0);
        __builtin_amdgcn_s_setprio(0);

        if (it + 1 < nh) load_k(kn, 4 * (it + 1) + kvq);  // prefetch next K

        // ---- mask, skipped for fully-valid tiles (wave-uniform) ----
        if (vlen < (tile + 1) * KVB) {
            const int kvb0 = tile * KVB + 4 * hi;
#pragma unroll
            for (int s = 0; s < 2; ++s) {
                const int vlim = vlen - (kvb0 + s * 32);
#pragma unroll
                for (int r = 0; r < 16; ++r) {
                    const int rc = (r & 3) + 8 * (r >> 2);
                    acs[s][r] = (rc < vlim) ? acs[s][r] : NEG_INF;
                }
            }
        }

        // ---- row max: depth-5 tree + 1 shuffle ----
        float mx[8];
#pragma unroll
        for (int r = 0; r < 8; ++r)
            mx[r] = fmaxf(fmaxf(acs[0][r], acs[0][r + 8]),
                          fmaxf(acs[1][r], acs[1][r + 8]));
#pragma unroll
        for (int d = 4; d; d >>= 1)
#pragma unroll
            for (int r = 0; r < d; ++r) mx[r] = fmaxf(mx[r], mx[r + d]);
        float xv = mx[0];
        xv = fmaxf(xv, __shfl_xor(xv, 32, 64));

        // ---- T13 defer-max (rescale BOTH accumulator sets; rare) ----
        float mn = m;
        if (!__all(xv <= m + 8.f)) {
            mn = fmaxf(m, xv);
            const float alpha = fexp2(m - mn);   // m=-inf first -> 0
            m = mn;
            lsum *= alpha;
#pragma unroll
            for (int r = 0; r < 16; ++r) {
                const int rc = (r & 3) + 8 * (r >> 2);
                const float ar = __shfl(alpha, rc + 4 * hi, 64);
                acc_oA[0][r] *= ar; acc_oA[1][r] *= ar;
                acc_oB[0][r] *= ar; acc_oB[1][r] *= ar;
            }
        }

        // ---- P = 2^(s - mn); sum as tree + 1 shuffle ----
#pragma unroll
        for (int s = 0; s < 2; ++s)
#pragma unroll
            for (int r = 0; r < 16; ++r) acs[s][r] = fexp2(acs[s][r] - mn);
        float sm[8];
#pragma unroll
        for (int r = 0; r < 8; ++r)
            sm[r] = (acs[0][r] + acs[0][r + 8]) + (acs[1][r] + acs[1][r + 8]);
#pragma unroll
        for (int d = 4; d; d >>= 1)
#pragma unroll
            for (int r = 0; r < d; ++r) sm[r] += sm[r + d];
        float rs = sm[0];
        rs += __shfl_xor(rs, 32, 64);
        lsum += rs;

        // ---- P -> bf16 packs (16 cvt_pk) ----
        unsigned pk[2][4][2];
#pragma unroll
        for (int s = 0; s < 2; ++s)
#pragma unroll
            for (int be = 0; be < 4; ++be)
#pragma unroll
                for (int c = 0; c < 2; ++c)
                    asm("v_cvt_pk_bf16_f32 %0, %1, %2"
                        : "=v"(pk[s][be][c])
                        : "v"(acs[s][4 * be + 2 * c]),
                          "v"(acs[s][4 * be + 2 * c + 1]));

        // ---- O(me) += P V: 8 permlane32_swap build A-frags in-register ----
        __builtin_amdgcn_s_setprio(1);
#pragma unroll
        for (int ks = 0; ks < 4; ++ks) {
            const int s = ks >> 1, g = ks & 1;
            unsigned w0 = pk[s][2 * g][0], w2 = pk[s][2 * g + 1][0];
            unsigned w1 = pk[s][2 * g][1], w3 = pk[s][2 * g + 1][1];
            asm("v_permlane32_swap_b32 %0, %1" : "+v"(w0), "+v"(w2));
            asm("v_permlane32_swap_b32 %0, %1" : "+v"(w1), "+v"(w3));
            union { unsigned u[4]; short8 s8; } pf;
            pf.u[0] = w0; pf.u[1] = w1; pf.u[2] = w2; pf.u[3] = w3;
#pragma unroll
            for (int t = 0; t < 2; ++t)
                am[t] = __builtin_amdgcn_mfma_f32_32x32x16_bf16(
                    pf.s8, vfr[t * 4 + ks], am[t], 0, 0, 0);
        }
        __builtin_amdgcn_s_setprio(0);
    };

    if (nh > 0) load_k(kf0, kvq);
    int it = 0;
    for (; it + 1 < nh; it += 2) {         // A/B alternate: independent chains
        body(kf0, kf1, acc_oA, it);
        body(kf1, kf0, acc_oB, it + 1);
    }
    if (it < nh) body(kf0, kf1, acc_oA, it);

#pragma unroll
    for (int t = 0; t < 2; ++t)
#pragma unroll
        for (int r = 0; r < 16; ++r) acc_oA[t][r] += acc_oB[t][r];

    // ---- 4-way merge across KV quarters (shuffle-free, verified R10) ----
#pragma unroll
    for (int t = 0; t < 2; ++t)
#pragma unroll
        for (int r = 0; r < 16; ++r) {
            const int rc = (r & 3) + 8 * (r >> 2);
            mrg[qsub][kvq][rc + 4 * hi][t * 32 + l31] = acc_oA[t][r];
        }
    if (lane < 32) mlb[qsub][kvq][l31] = float2{m, lsum};
    __syncthreads();

    // epilogue: each wave outputs 8 q-rows of its qsub group
    {
        const int qsubo = wave >> 2;
        const int qq = (wave & 3) * 8 + (lane >> 3);
        const int dg = (lane & 7) * 8;
        float mi[4], li[4];
#pragma unroll
        for (int ii = 0; ii < 4; ++ii) {
            const float2 c = mlb[qsubo][ii][qq];
            mi[ii] = c.x; li[ii] = c.y;
        }
        const float M = fmaxf(fmaxf(mi[0], mi[1]), fmaxf(mi[2], mi[3]));
        float wgt[4], L = 0.f;
#pragma unroll
        for (int ii = 0; ii < 4; ++ii) {
            wgt[ii] = fexp2(mi[ii] - M);       // mi=-inf -> 0
            L += li[ii] * wgt[ii];
        }
        const float Linv = 1.f / L;
#pragma unroll
        for (int ii = 0; ii < 4; ++ii) wgt[ii] *= Linv;

        float4v o0 = {0.f, 0.f, 0.f, 0.f}, o1 = {0.f, 0.f, 0.f, 0.f};
#pragma unroll
        for (int ii = 0; ii < 4; ++ii) {
            const float* src = &mrg[qsubo][ii][qq][dg];
            float4v a = *reinterpret_cast<const float4v*>(src);
            float4v c = *reinterpret_cast<const float4v*>(src + 4);
#pragma unroll
            for (int j = 0; j < 4; ++j) {
                o0[j] += a[j] * wgt[ii]; o1[j] += c[j] * wgt[ii];
            }
        }
        float* Ob = O + ((size_t)b * NQ + qt * 64 + qsubo * 32 + qq) * DH + dg;
        *reinterpret_cast<float4v*>(Ob)     = o0;
        *reinterpret_cast<float4v*>(Ob + 4) = o1;
    }
}

extern "C" void kernel_launch(void* const* d_in, const int* in_sizes, int n_in,
                              void* d_out, int out_size, void* d_ws, size_t ws_size,
                              hipStream_t stream) {
    const float* Q = (const float*)d_in[0];
    const float* K = (const float*)d_in[1];
    const float* V = (const float*)d_in[2];
    const int* vl  = (const int*)d_in[3];
    float* Out     = (float*)d_out;

    short* Kws = (short*)d_ws;
    short* Vws = Kws + (size_t)BATCH * NTILES * TILE_ELEMS;

    prep_kernel<<<dim3(BATCH * NTILES), dim3(256), 0, stream>>>(K, V, vl, Kws, Vws);
    attn_fwd_kernel<<<dim3(512), dim3(512), 0, stream>>>(Q, Kws, Vws, vl, Out);
}